// Round 8
// baseline (442.135 us; speedup 1.0000x reference)
//
#include <hip/hip_runtime.h>
#include <math.h>

// ---------------------------------------------------------------------------
// TrafficGNN: 2-layer GCN + BN + ReLU + log_softmax.
// Round 8: (a) 8-way split counters for k_cnt (same-line atomic contention
// 16 -> 2 expected collisions per counter line); (b) k_nrm deleted, edge
// weight normalization folded into the gathers (dinv is L2-resident).
// ---------------------------------------------------------------------------

typedef unsigned int   uint;
typedef unsigned short ushort;
typedef __bf16 bf16x8 __attribute__((ext_vector_type(8)));
typedef float  f32x4  __attribute__((ext_vector_type(4)));

union U16 { uint4 u; bf16x8 b; };

__device__ __forceinline__ void atomAddF(float* p, float v) {
    __hip_atomic_fetch_add(p, v, __ATOMIC_RELAXED, __HIP_MEMORY_SCOPE_AGENT);
}

// float -> bf16 (round to nearest even)
__device__ __forceinline__ ushort f2bf(float f) {
    uint u = __float_as_uint(f);
    u += 0x7FFFu + ((u >> 16) & 1u);
    return (ushort)(u >> 16);
}
__device__ __forceinline__ float bf2f(ushort h) {
    return __uint_as_float(((uint)h) << 16);
}
__device__ __forceinline__ uint pack2(float f0, float f1) {
    return (uint)f2bf(f0) | ((uint)f2bf(f1) << 16);
}

// zero 8-way edge counters (8n ints) + BN accumulators
__global__ void k_init(int* __restrict__ cnt, float* __restrict__ bn, int m) {
    int i = blockIdx.x * 256 + threadIdx.x;
    if (i < m) cnt[i] = 0;
    if (i < 256) bn[i] = 0.0f;   // bn[0..127]=sum, bn[128..255]=sumsq
}

// rank[i] = slot within (target, copy) bucket; copy = i&7 (8-way decontention)
__global__ void k_cnt(const int* __restrict__ col, int* __restrict__ cnt,
                      int* __restrict__ rank, int e) {
    int i = blockIdx.x * 256 + threadIdx.x;
    if (i < e) rank[i] = atomicAdd(&cnt[(col[i] << 3) + (i & 7)], 1);
}

// ---- exclusive scan of cnt[m] -> ptr[m+1]  (m = 8n) ----

__global__ __launch_bounds__(256)
void k_scanA(const int* __restrict__ cnt, int* __restrict__ bsum, int m) {
    __shared__ int ls[256];
    int base = blockIdx.x * 1024 + threadIdx.x * 4;
    int s = 0;
#pragma unroll
    for (int k = 0; k < 4; ++k) { int i = base + k; if (i < m) s += cnt[i]; }
    ls[threadIdx.x] = s;
    __syncthreads();
    for (int d = 128; d > 0; d >>= 1) {
        if (threadIdx.x < d) ls[threadIdx.x] += ls[threadIdx.x + d];
        __syncthreads();
    }
    if (threadIdx.x == 0) bsum[blockIdx.x] = ls[0];
}

__global__ void k_scanB(int* __restrict__ bsum, int* __restrict__ ptr,
                        int nblk, int m) {
    if (threadIdx.x == 0) {
        int run = 0;
        for (int i = 0; i < nblk; ++i) { int v = bsum[i]; bsum[i] = run; run += v; }
        ptr[m] = run;
    }
}

__global__ __launch_bounds__(256)
void k_scanC(const int* __restrict__ cnt, const int* __restrict__ bsum,
             int* __restrict__ ptr, int m) {
    __shared__ int ls[256];
    int base = blockIdx.x * 1024 + threadIdx.x * 4;
    int v[4];
#pragma unroll
    for (int k = 0; k < 4; ++k) { int i = base + k; v[k] = (i < m) ? cnt[i] : 0; }
    int t = v[0] + v[1] + v[2] + v[3];
    ls[threadIdx.x] = t;
    __syncthreads();
    for (int d = 1; d < 256; d <<= 1) {
        int mine = ls[threadIdx.x];
        int up   = (threadIdx.x >= d) ? ls[threadIdx.x - d] : 0;
        __syncthreads();
        ls[threadIdx.x] = mine + up;
        __syncthreads();
    }
    int off = bsum[blockIdx.x] + ls[threadIdx.x] - t;   // exclusive
    int pf = 0;
#pragma unroll
    for (int k = 0; k < 4; ++k) {
        int i = base + k;
        if (i < m) ptr[i] = off + pf;
        pf += v[k];
    }
}

// atomic-free CSR fill: slot = ptr8[tgt*8 + copy] + rank; store (src, raw ew)
__global__ void k_fill(const int* __restrict__ row, const int* __restrict__ col,
                       const float* __restrict__ ew, const int* __restrict__ rank,
                       const int* __restrict__ ptr, int2* __restrict__ csr, int e) {
    int i = blockIdx.x * 256 + threadIdx.x;
    if (i < e) {
        int pos = ptr[(col[i] << 3) + (i & 7)] + rank[i];
        int2 pr;
        pr.x = row[i];
        pr.y = __float_as_int(ew[i]);
        csr[pos] = pr;
    }
}

// dinv[i] = rsqrt(1 + sum of raw ew over node segment)   (16 lanes per node)
__global__ __launch_bounds__(256)
void k_degsum(const int* __restrict__ ptr, const int2* __restrict__ csr,
              float* __restrict__ dinv, int n) {
    int lane = threadIdx.x & 15;
    int node = (blockIdx.x * 256 + threadIdx.x) >> 4;
    if (node >= n) return;
    int p0 = ptr[node << 3], p1 = ptr[(node << 3) + 8];
    float s = 0.f;
    for (int j = p0 + lane; j < p1; j += 16) s += __int_as_float(csr[j].y);
#pragma unroll
    for (int off = 8; off > 0; off >>= 1) s += __shfl_xor(s, off, 16);
    if (lane == 0) dinv[node] = rsqrtf(1.0f + s);
}

// W[128][M] f32 row-major -> bf16 fragment order: frag[(nt*4+ks)*64+l][j] =
// W[ks*32 + (l>>4)*8 + j][nt*16 + (l&15)].  One thread per fragment.
__global__ void k_wfrag(const float* __restrict__ W, uint4* __restrict__ Wf, int M) {
    int t = blockIdx.x * 256 + threadIdx.x;
    if (t >= M * 16) return;
    int l  = t & 63;
    int ks = (t >> 6) & 3;
    int nt = t >> 8;
    int kbase = ks * 32 + (l >> 4) * 8;
    int colj  = nt * 16 + (l & 15);
    float v[8];
#pragma unroll
    for (int j = 0; j < 8; ++j) v[j] = W[(kbase + j) * M + colj];
    uint4 o;
    o.x = pack2(v[0], v[1]);
    o.y = pack2(v[2], v[3]);
    o.z = pack2(v[4], v[5]);
    o.w = pack2(v[6], v[7]);
    Wf[t] = o;
}

// H[n,M](bf16) = X'[n,128](f32) @ W[128,M] via 16x16x32 bf16 MFMA.
template<int M, bool BN>
__global__ __launch_bounds__(256)
void k_mfma(const float* __restrict__ X, const uint4* __restrict__ Wf,
            const float* __restrict__ scale, const float* __restrict__ shift,
            ushort* __restrict__ H, int n)
{
    constexpr int NT = M / 16;
    const int l = threadIdx.x & 63;
    const int w = threadIdx.x >> 6;
    const int rowbase = blockIdx.x * 64 + w * 16;
    const int arow = rowbase + (l & 15);
    const bool rv = arow < n;
    const int koff = (l >> 4) * 8;

    f32x4 acc[NT];
#pragma unroll
    for (int t = 0; t < NT; ++t) acc[t] = (f32x4){0.f, 0.f, 0.f, 0.f};

    const float* xr = X + (size_t)arow * 128 + koff;

#pragma unroll
    for (int ks = 0; ks < 4; ++ks) {
        float4 a0 = make_float4(0.f, 0.f, 0.f, 0.f);
        float4 a1 = a0;
        if (rv) {
            a0 = *(const float4*)(xr + ks * 32);
            a1 = *(const float4*)(xr + ks * 32 + 4);
        }
        if (BN) {
            int k0 = ks * 32 + koff;
            float4 sc0 = *(const float4*)(scale + k0);
            float4 sc1 = *(const float4*)(scale + k0 + 4);
            float4 sh0 = *(const float4*)(shift + k0);
            float4 sh1 = *(const float4*)(shift + k0 + 4);
            a0.x = fmaxf(0.f, fmaf(a0.x, sc0.x, sh0.x));
            a0.y = fmaxf(0.f, fmaf(a0.y, sc0.y, sh0.y));
            a0.z = fmaxf(0.f, fmaf(a0.z, sc0.z, sh0.z));
            a0.w = fmaxf(0.f, fmaf(a0.w, sc0.w, sh0.w));
            a1.x = fmaxf(0.f, fmaf(a1.x, sc1.x, sh1.x));
            a1.y = fmaxf(0.f, fmaf(a1.y, sc1.y, sh1.y));
            a1.z = fmaxf(0.f, fmaf(a1.z, sc1.z, sh1.z));
            a1.w = fmaxf(0.f, fmaf(a1.w, sc1.w, sh1.w));
        }
        U16 ua;
        ua.u.x = pack2(a0.x, a0.y);
        ua.u.y = pack2(a0.z, a0.w);
        ua.u.z = pack2(a1.x, a1.y);
        ua.u.w = pack2(a1.z, a1.w);
#pragma unroll
        for (int nt = 0; nt < NT; ++nt) {
            U16 ub;
            ub.u = Wf[(nt * 4 + ks) * 64 + l];
            acc[nt] = __builtin_amdgcn_mfma_f32_16x16x32_bf16(ua.b, ub.b, acc[nt], 0, 0, 0);
        }
    }

    // epilogue: transpose through padded LDS, then coalesced 16B stores.
    __shared__ __align__(16) ushort lds[4][16][M + 8];
#pragma unroll
    for (int nt = 0; nt < NT; ++nt)
#pragma unroll
        for (int r = 0; r < 4; ++r)
            lds[w][(l >> 4) * 4 + r][nt * 16 + (l & 15)] = f2bf(acc[nt][r]);
    __syncthreads();

    constexpr int LPR = M / 8;
    constexpr int RPP = 64 / LPR;
#pragma unroll
    for (int it = 0; it < 16 / RPP; ++it) {
        int rl = it * RPP + (l / LPR);
        int gr = rowbase + rl;
        if (gr < n)
            *(uint4*)(H + (size_t)gr * M + (l % LPR) * 8) =
                *(const uint4*)&lds[w][rl][(l % LPR) * 8];
    }
}

// layer-1 gather: out(f32) = b1 + h[i]*dinv^2 + sum h[src]*(ew*dinv[src]*di)
__global__ __launch_bounds__(256)
void k_gather1(const int* __restrict__ ptr, const int2* __restrict__ csr,
               const ushort* __restrict__ h, const float* __restrict__ dinv,
               const float* __restrict__ bias, float* __restrict__ out, int n)
{
    int lane = threadIdx.x & 63;
    int node = (blockIdx.x * 256 + threadIdx.x) >> 6;
    if (node >= n) return;
    int p0 = ptr[node << 3], p1 = ptr[(node << 3) + 8];
    float di = dinv[node];
    float s  = di * di;
    uint hv = *(const uint*)(h + (size_t)node * 128 + lane * 2);
    float2 bv = *(const float2*)(bias + lane * 2);
    float accx = fmaf(bf2f((ushort)hv), s, bv.x);
    float accy = fmaf(bf2f((ushort)(hv >> 16)), s, bv.y);
#pragma unroll 4
    for (int j = p0; j < p1; ++j) {
        int2 pr = csr[j];
        float w = __int_as_float(pr.y) * di * dinv[pr.x];
        uint v = *(const uint*)(h + (size_t)pr.x * 128 + lane * 2);
        accx = fmaf(bf2f((ushort)v), w, accx);
        accy = fmaf(bf2f((ushort)(v >> 16)), w, accy);
    }
    *(float2*)(out + (size_t)node * 128 + lane * 2) = make_float2(accx, accy);
}

// layer-2 gather + fused log_softmax
__global__ __launch_bounds__(256)
void k_gather2(const int* __restrict__ ptr, const int2* __restrict__ csr,
               const ushort* __restrict__ h, const float* __restrict__ dinv,
               const float* __restrict__ bias, float* __restrict__ out, int n)
{
    int lane = threadIdx.x & 63;
    int node = (blockIdx.x * 256 + threadIdx.x) >> 6;
    if (node >= n) return;
    int p0 = ptr[node << 3], p1 = ptr[(node << 3) + 8];
    float di = dinv[node];
    float s  = di * di;
    float acc = fmaf(bf2f(h[(size_t)node * 64 + lane]), s, bias[lane]);
#pragma unroll 4
    for (int j = p0; j < p1; ++j) {
        int2 pr = csr[j];
        float w = __int_as_float(pr.y) * di * dinv[pr.x];
        acc = fmaf(bf2f(h[(size_t)pr.x * 64 + lane]), w, acc);
    }
    float m = acc;
#pragma unroll
    for (int off = 32; off > 0; off >>= 1) m = fmaxf(m, __shfl_xor(m, off, 64));
    float ex = expf(acc - m);
    float sum = ex;
#pragma unroll
    for (int off = 32; off > 0; off >>= 1) sum += __shfl_xor(sum, off, 64);
    out[(size_t)node * 64 + lane] = acc - m - logf(sum);
}

// per-feature sum & sumsq over nodes (128 feats)
__global__ __launch_bounds__(256)
void k_bn_stats(const float* __restrict__ a, float* __restrict__ sums,
                float* __restrict__ sumsq, int n)
{
    int f = threadIdx.x & 127;
    int r0 = blockIdx.x * 2 + (threadIdx.x >> 7);
    float s = 0.f, q = 0.f;
    for (int r = r0; r < n; r += gridDim.x * 2) {
        float v = a[(size_t)r * 128 + f];
        s += v; q += v * v;
    }
    __shared__ float ls[256], lq[256];
    ls[threadIdx.x] = s; lq[threadIdx.x] = q;
    __syncthreads();
    if (threadIdx.x < 128) {
        atomAddF(&sums[f],  ls[threadIdx.x] + ls[threadIdx.x + 128]);
        atomAddF(&sumsq[f], lq[threadIdx.x] + lq[threadIdx.x + 128]);
    }
}

__global__ void k_bn_final(const float* __restrict__ bn, const float* __restrict__ gamma,
                           const float* __restrict__ beta, float* __restrict__ scale,
                           float* __restrict__ shift, int n)
{
    int f = threadIdx.x;
    if (f < 128) {
        float inv_n = 1.0f / (float)n;
        float mu  = bn[f] * inv_n;
        float var = bn[128 + f] * inv_n - mu * mu;
        float rstd = rsqrtf(var + 1e-5f);
        float sc = gamma[f] * rstd;
        scale[f] = sc;
        shift[f] = beta[f] - mu * sc;
    }
}

extern "C" void kernel_launch(void* const* d_in, const int* in_sizes, int n_in,
                              void* d_out, int out_size, void* d_ws, size_t ws_size,
                              hipStream_t stream)
{
    const float* x     = (const float*)d_in[0];
    const int*   ei    = (const int*)  d_in[1];
    const float* ew    = (const float*)d_in[2];
    const float* W1    = (const float*)d_in[3];
    const float* b1    = (const float*)d_in[4];
    const float* gamma = (const float*)d_in[5];
    const float* beta  = (const float*)d_in[6];
    const float* W2    = (const float*)d_in[7];
    const float* b2    = (const float*)d_in[8];

    const int n = in_sizes[0] / 128;   // 100000
    const int e = in_sizes[2];         // 1600000
    const int* row = ei;               // edge_index[0]  (source)
    const int* col = ei + e;           // edge_index[1]  (target)
    const int m = n * 8;               // split-counter count

    // workspace layout (4-byte units):
    // dinv[n] | h1 bf16[n*128] (h2 aliases) | agg1 f32[n*128] (rank aliases) |
    // bn[256] | scale[128] | shift[128] | cnt8[8n] | ptr8[8n+1] | bsum[1024] |
    // w1f[8192 f32] | w2f[4096 f32] | csr[e] (int2)
    float* ws    = (float*)d_ws;
    size_t off   = 0;
    float* dinv  = ws + off; off += n;
    ushort* h1   = (ushort*)(ws + off); off += (size_t)n * 64;  // n*128 bf16
    float* agg1  = ws + off; off += (size_t)n * 128;
    float* bn    = ws + off; off += 256;
    float* scale = ws + off; off += 128;
    float* shift = ws + off; off += 128;
    int*   cnt   = (int*)(ws + off); off += (size_t)m;
    int*   ptr   = (int*)(ws + off); off += (size_t)(m + 1);
    int*   bsum  = (int*)(ws + off); off += 1024;
    off = (off + 3) & ~(size_t)3;       // 16-byte align for uint4
    uint4* w1f   = (uint4*)(ws + off); off += 8192;  // 128*128 bf16 = 2048 uint4
    uint4* w2f   = (uint4*)(ws + off); off += 4096;  // 128*64  bf16 = 1024 uint4
    int2*  csr   = (int2*)(ws + off);
    int*   rank  = (int*)agg1;          // agg1 dead until k_gather1
    ushort* h2   = h1;                  // h1 dead after k_gather1
    float* outp  = (float*)d_out;

    const int nb_m = (m + 255) / 256;
    const int nb_e = (e + 255) / 256;
    const int nb_wpn = (n + 3) / 4;     // wave-per-node: n*64 threads
    const int nb_qpn = (n + 15) / 16;   // 16-lane-group-per-node
    const int nb_mf  = (n + 63) / 64;   // MFMA gemm: 64 rows/block
    const int nblk_scan = (m + 1023) / 1024;   // 782 <= bsum capacity 1024

    // W fragment swizzle (no deps)
    k_wfrag<<<8, 256, 0, stream>>>(W1, w1f, 128);
    k_wfrag<<<4, 256, 0, stream>>>(W2, w2f, 64);

    // CSR build: count(+rank, 8-way split) -> scan -> fill -> degsum
    k_init<<<nb_m, 256, 0, stream>>>(cnt, bn, m);
    k_cnt<<<nb_e, 256, 0, stream>>>(col, cnt, rank, e);
    k_scanA<<<nblk_scan, 256, 0, stream>>>(cnt, bsum, m);
    k_scanB<<<1, 64, 0, stream>>>(bsum, ptr, nblk_scan, m);
    k_scanC<<<nblk_scan, 256, 0, stream>>>(cnt, bsum, ptr, m);
    k_fill<<<nb_e, 256, 0, stream>>>(row, col, ew, rank, ptr, csr, e);
    k_degsum<<<nb_qpn, 256, 0, stream>>>(ptr, csr, dinv, n);

    // ---- layer 1: h1 = x @ W1 (bf16, MFMA) ; agg1 = gather(h1) + b1 ----
    k_mfma<128, false><<<nb_mf, 256, 0, stream>>>(x, w1f, nullptr, nullptr, h1, n);
    k_gather1<<<nb_wpn, 256, 0, stream>>>(ptr, csr, h1, dinv, b1, agg1, n);

    // ---- batchnorm stats -> scale/shift ----
    k_bn_stats<<<256, 256, 0, stream>>>(agg1, bn, bn + 128, n);
    k_bn_final<<<1, 128, 0, stream>>>(bn, gamma, beta, scale, shift, n);

    // ---- layer 2: h2 = relu(bn(agg1)) @ W2 (bf16, MFMA) ; out + lsm ----
    k_mfma<64, true><<<nb_mf, 256, 0, stream>>>(agg1, w2f, scale, shift, h2, n);
    k_gather2<<<nb_wpn, 256, 0, stream>>>(ptr, csr, h2, dinv, b2, outp, n);
}

// Round 9
// 350.987 us; speedup vs baseline: 1.2597x; 1.2597x over previous
//
#include <hip/hip_runtime.h>
#include <math.h>

// ---------------------------------------------------------------------------
// TrafficGNN: 2-layer GCN + BN + ReLU + log_softmax.
// Round 9: revert 8-way split counters (R8 post-mortem: k_cnt is atomic-
// throughput-bound, not contention-bound; the split only blew up the serial
// scanB 10->80us). Parallel scanB (Hillis-Steele). k_gather1 remapped to
// 16-lane-group-per-node (4 nodes/wave, uint4 h-loads) for 4x MLP.
// ---------------------------------------------------------------------------

typedef unsigned int   uint;
typedef unsigned short ushort;
typedef __bf16 bf16x8 __attribute__((ext_vector_type(8)));
typedef float  f32x4  __attribute__((ext_vector_type(4)));

union U16 { uint4 u; bf16x8 b; };

__device__ __forceinline__ void atomAddF(float* p, float v) {
    __hip_atomic_fetch_add(p, v, __ATOMIC_RELAXED, __HIP_MEMORY_SCOPE_AGENT);
}

// float -> bf16 (round to nearest even)
__device__ __forceinline__ ushort f2bf(float f) {
    uint u = __float_as_uint(f);
    u += 0x7FFFu + ((u >> 16) & 1u);
    return (ushort)(u >> 16);
}
__device__ __forceinline__ float bf2f(ushort h) {
    return __uint_as_float(((uint)h) << 16);
}
__device__ __forceinline__ uint pack2(float f0, float f1) {
    return (uint)f2bf(f0) | ((uint)f2bf(f1) << 16);
}

// zero edge counters + zero BN accumulators
__global__ void k_init(int* __restrict__ cnt, float* __restrict__ bn, int n) {
    int i = blockIdx.x * 256 + threadIdx.x;
    if (i < n) cnt[i] = 0;
    if (i < 256) bn[i] = 0.0f;   // bn[0..127]=sum, bn[128..255]=sumsq
}

// rank[i] = slot index of edge i within its target's segment
__global__ void k_cnt(const int* __restrict__ col, int* __restrict__ cnt,
                      int* __restrict__ rank, int e) {
    int i = blockIdx.x * 256 + threadIdx.x;
    if (i < e) rank[i] = atomicAdd(&cnt[col[i]], 1);
}

// ---- exclusive scan of cnt[n] -> ptr[n+1] ----

__global__ __launch_bounds__(256)
void k_scanA(const int* __restrict__ cnt, int* __restrict__ bsum, int n) {
    __shared__ int ls[256];
    int base = blockIdx.x * 1024 + threadIdx.x * 4;
    int s = 0;
#pragma unroll
    for (int k = 0; k < 4; ++k) { int i = base + k; if (i < n) s += cnt[i]; }
    ls[threadIdx.x] = s;
    __syncthreads();
    for (int d = 128; d > 0; d >>= 1) {
        if (threadIdx.x < d) ls[threadIdx.x] += ls[threadIdx.x + d];
        __syncthreads();
    }
    if (threadIdx.x == 0) bsum[blockIdx.x] = ls[0];
}

// parallel exclusive scan of block sums (nblk <= 1024); also ptr[n] = total
__global__ __launch_bounds__(1024)
void k_scanB(int* __restrict__ bsum, int* __restrict__ ptr, int nblk, int n) {
    __shared__ int ls[1024];
    int t = threadIdx.x;
    int v = (t < nblk) ? bsum[t] : 0;
    ls[t] = v;
    __syncthreads();
    for (int d = 1; d < 1024; d <<= 1) {
        int mine = ls[t];
        int up   = (t >= d) ? ls[t - d] : 0;
        __syncthreads();
        ls[t] = mine + up;
        __syncthreads();
    }
    if (t < nblk) bsum[t] = ls[t] - v;   // exclusive
    if (t == 0) ptr[n] = ls[1023];       // total
}

__global__ __launch_bounds__(256)
void k_scanC(const int* __restrict__ cnt, const int* __restrict__ bsum,
             int* __restrict__ ptr, int n) {
    __shared__ int ls[256];
    int base = blockIdx.x * 1024 + threadIdx.x * 4;
    int v[4];
#pragma unroll
    for (int k = 0; k < 4; ++k) { int i = base + k; v[k] = (i < n) ? cnt[i] : 0; }
    int t = v[0] + v[1] + v[2] + v[3];
    ls[threadIdx.x] = t;
    __syncthreads();
    for (int d = 1; d < 256; d <<= 1) {
        int mine = ls[threadIdx.x];
        int up   = (threadIdx.x >= d) ? ls[threadIdx.x - d] : 0;
        __syncthreads();
        ls[threadIdx.x] = mine + up;
        __syncthreads();
    }
    int off = bsum[blockIdx.x] + ls[threadIdx.x] - t;   // exclusive
    int pf = 0;
#pragma unroll
    for (int k = 0; k < 4; ++k) {
        int i = base + k;
        if (i < n) ptr[i] = off + pf;
        pf += v[k];
    }
}

// atomic-free CSR fill: slot = ptr[tgt] + rank; store (src, raw ew) pair
__global__ void k_fill(const int* __restrict__ row, const int* __restrict__ col,
                       const float* __restrict__ ew, const int* __restrict__ rank,
                       const int* __restrict__ ptr, int2* __restrict__ csr, int e) {
    int i = blockIdx.x * 256 + threadIdx.x;
    if (i < e) {
        int pos = ptr[col[i]] + rank[i];
        int2 pr;
        pr.x = row[i];
        pr.y = __float_as_int(ew[i]);
        csr[pos] = pr;
    }
}

// dinv[i] = rsqrt(1 + sum of raw ew over segment)    (16 lanes per node)
__global__ __launch_bounds__(256)
void k_degsum(const int* __restrict__ ptr, const int2* __restrict__ csr,
              float* __restrict__ dinv, int n) {
    int lane = threadIdx.x & 15;
    int node = (blockIdx.x * 256 + threadIdx.x) >> 4;
    if (node >= n) return;
    int p0 = ptr[node], p1 = ptr[node + 1];
    float s = 0.f;
    for (int j = p0 + lane; j < p1; j += 16) s += __int_as_float(csr[j].y);
#pragma unroll
    for (int off = 8; off > 0; off >>= 1) s += __shfl_xor(s, off, 16);
    if (lane == 0) dinv[node] = rsqrtf(1.0f + s);
}

// W[128][M] f32 row-major -> bf16 fragment order (one thread per fragment)
__global__ void k_wfrag(const float* __restrict__ W, uint4* __restrict__ Wf, int M) {
    int t = blockIdx.x * 256 + threadIdx.x;
    if (t >= M * 16) return;
    int l  = t & 63;
    int ks = (t >> 6) & 3;
    int nt = t >> 8;
    int kbase = ks * 32 + (l >> 4) * 8;
    int colj  = nt * 16 + (l & 15);
    float v[8];
#pragma unroll
    for (int j = 0; j < 8; ++j) v[j] = W[(kbase + j) * M + colj];
    uint4 o;
    o.x = pack2(v[0], v[1]);
    o.y = pack2(v[2], v[3]);
    o.z = pack2(v[4], v[5]);
    o.w = pack2(v[6], v[7]);
    Wf[t] = o;
}

// H[n,M](bf16) = X'[n,128](f32) @ W[128,M] via 16x16x32 bf16 MFMA.
template<int M, bool BN>
__global__ __launch_bounds__(256)
void k_mfma(const float* __restrict__ X, const uint4* __restrict__ Wf,
            const float* __restrict__ scale, const float* __restrict__ shift,
            ushort* __restrict__ H, int n)
{
    constexpr int NT = M / 16;
    const int l = threadIdx.x & 63;
    const int w = threadIdx.x >> 6;
    const int rowbase = blockIdx.x * 64 + w * 16;
    const int arow = rowbase + (l & 15);
    const bool rv = arow < n;
    const int koff = (l >> 4) * 8;

    f32x4 acc[NT];
#pragma unroll
    for (int t = 0; t < NT; ++t) acc[t] = (f32x4){0.f, 0.f, 0.f, 0.f};

    const float* xr = X + (size_t)arow * 128 + koff;

#pragma unroll
    for (int ks = 0; ks < 4; ++ks) {
        float4 a0 = make_float4(0.f, 0.f, 0.f, 0.f);
        float4 a1 = a0;
        if (rv) {
            a0 = *(const float4*)(xr + ks * 32);
            a1 = *(const float4*)(xr + ks * 32 + 4);
        }
        if (BN) {
            int k0 = ks * 32 + koff;
            float4 sc0 = *(const float4*)(scale + k0);
            float4 sc1 = *(const float4*)(scale + k0 + 4);
            float4 sh0 = *(const float4*)(shift + k0);
            float4 sh1 = *(const float4*)(shift + k0 + 4);
            a0.x = fmaxf(0.f, fmaf(a0.x, sc0.x, sh0.x));
            a0.y = fmaxf(0.f, fmaf(a0.y, sc0.y, sh0.y));
            a0.z = fmaxf(0.f, fmaf(a0.z, sc0.z, sh0.z));
            a0.w = fmaxf(0.f, fmaf(a0.w, sc0.w, sh0.w));
            a1.x = fmaxf(0.f, fmaf(a1.x, sc1.x, sh1.x));
            a1.y = fmaxf(0.f, fmaf(a1.y, sc1.y, sh1.y));
            a1.z = fmaxf(0.f, fmaf(a1.z, sc1.z, sh1.z));
            a1.w = fmaxf(0.f, fmaf(a1.w, sc1.w, sh1.w));
        }
        U16 ua;
        ua.u.x = pack2(a0.x, a0.y);
        ua.u.y = pack2(a0.z, a0.w);
        ua.u.z = pack2(a1.x, a1.y);
        ua.u.w = pack2(a1.z, a1.w);
#pragma unroll
        for (int nt = 0; nt < NT; ++nt) {
            U16 ub;
            ub.u = Wf[(nt * 4 + ks) * 64 + l];
            acc[nt] = __builtin_amdgcn_mfma_f32_16x16x32_bf16(ua.b, ub.b, acc[nt], 0, 0, 0);
        }
    }

    __shared__ __align__(16) ushort lds[4][16][M + 8];
#pragma unroll
    for (int nt = 0; nt < NT; ++nt)
#pragma unroll
        for (int r = 0; r < 4; ++r)
            lds[w][(l >> 4) * 4 + r][nt * 16 + (l & 15)] = f2bf(acc[nt][r]);
    __syncthreads();

    constexpr int LPR = M / 8;
    constexpr int RPP = 64 / LPR;
#pragma unroll
    for (int it = 0; it < 16 / RPP; ++it) {
        int rl = it * RPP + (l / LPR);
        int gr = rowbase + rl;
        if (gr < n)
            *(uint4*)(H + (size_t)gr * M + (l % LPR) * 8) =
                *(const uint4*)&lds[w][rl][(l % LPR) * 8];
    }
}

// layer-1 gather, 16-lane group per node (4 nodes/wave, 4x MLP):
// each lane owns 8 contiguous bf16 features (one uint4 load per edge).
__global__ __launch_bounds__(256)
void k_gather1(const int* __restrict__ ptr, const int2* __restrict__ csr,
               const ushort* __restrict__ h, const float* __restrict__ dinv,
               const float* __restrict__ bias, float* __restrict__ out, int n)
{
    int lane = threadIdx.x & 15;
    int node = (blockIdx.x * 256 + threadIdx.x) >> 4;
    if (node >= n) return;
    int p0 = ptr[node], p1 = ptr[node + 1];
    float di = dinv[node];
    float s  = di * di;

    const ushort* hrow = h + (size_t)node * 128 + lane * 8;
    U16 hv; hv.u = *(const uint4*)hrow;
    float4 b0 = *(const float4*)(bias + lane * 8);
    float4 b1v = *(const float4*)(bias + lane * 8 + 4);
    float acc[8];
    acc[0] = fmaf(bf2f((ushort)(hv.u.x)),       s, b0.x);
    acc[1] = fmaf(bf2f((ushort)(hv.u.x >> 16)), s, b0.y);
    acc[2] = fmaf(bf2f((ushort)(hv.u.y)),       s, b0.z);
    acc[3] = fmaf(bf2f((ushort)(hv.u.y >> 16)), s, b0.w);
    acc[4] = fmaf(bf2f((ushort)(hv.u.z)),       s, b1v.x);
    acc[5] = fmaf(bf2f((ushort)(hv.u.z >> 16)), s, b1v.y);
    acc[6] = fmaf(bf2f((ushort)(hv.u.w)),       s, b1v.z);
    acc[7] = fmaf(bf2f((ushort)(hv.u.w >> 16)), s, b1v.w);

#pragma unroll 4
    for (int j = p0; j < p1; ++j) {
        int2 pr = csr[j];
        float w = __int_as_float(pr.y) * di * dinv[pr.x];
        U16 v; v.u = *(const uint4*)(h + (size_t)pr.x * 128 + lane * 8);
        acc[0] = fmaf(bf2f((ushort)(v.u.x)),       w, acc[0]);
        acc[1] = fmaf(bf2f((ushort)(v.u.x >> 16)), w, acc[1]);
        acc[2] = fmaf(bf2f((ushort)(v.u.y)),       w, acc[2]);
        acc[3] = fmaf(bf2f((ushort)(v.u.y >> 16)), w, acc[3]);
        acc[4] = fmaf(bf2f((ushort)(v.u.z)),       w, acc[4]);
        acc[5] = fmaf(bf2f((ushort)(v.u.z >> 16)), w, acc[5]);
        acc[6] = fmaf(bf2f((ushort)(v.u.w)),       w, acc[6]);
        acc[7] = fmaf(bf2f((ushort)(v.u.w >> 16)), w, acc[7]);
    }

    float* orow = out + (size_t)node * 128 + lane * 8;
    *(float4*)(orow)     = make_float4(acc[0], acc[1], acc[2], acc[3]);
    *(float4*)(orow + 4) = make_float4(acc[4], acc[5], acc[6], acc[7]);
}

// layer-2 gather + fused log_softmax (wave per node)
__global__ __launch_bounds__(256)
void k_gather2(const int* __restrict__ ptr, const int2* __restrict__ csr,
               const ushort* __restrict__ h, const float* __restrict__ dinv,
               const float* __restrict__ bias, float* __restrict__ out, int n)
{
    int lane = threadIdx.x & 63;
    int node = (blockIdx.x * 256 + threadIdx.x) >> 6;
    if (node >= n) return;
    int p0 = ptr[node], p1 = ptr[node + 1];
    float di = dinv[node];
    float s  = di * di;
    float acc = fmaf(bf2f(h[(size_t)node * 64 + lane]), s, bias[lane]);
#pragma unroll 4
    for (int j = p0; j < p1; ++j) {
        int2 pr = csr[j];
        float w = __int_as_float(pr.y) * di * dinv[pr.x];
        acc = fmaf(bf2f(h[(size_t)pr.x * 64 + lane]), w, acc);
    }
    float m = acc;
#pragma unroll
    for (int off = 32; off > 0; off >>= 1) m = fmaxf(m, __shfl_xor(m, off, 64));
    float ex = expf(acc - m);
    float sum = ex;
#pragma unroll
    for (int off = 32; off > 0; off >>= 1) sum += __shfl_xor(sum, off, 64);
    out[(size_t)node * 64 + lane] = acc - m - logf(sum);
}

// per-feature sum & sumsq over nodes (128 feats)
__global__ __launch_bounds__(256)
void k_bn_stats(const float* __restrict__ a, float* __restrict__ sums,
                float* __restrict__ sumsq, int n)
{
    int f = threadIdx.x & 127;
    int r0 = blockIdx.x * 2 + (threadIdx.x >> 7);
    float s = 0.f, q = 0.f;
    for (int r = r0; r < n; r += gridDim.x * 2) {
        float v = a[(size_t)r * 128 + f];
        s += v; q += v * v;
    }
    __shared__ float ls[256], lq[256];
    ls[threadIdx.x] = s; lq[threadIdx.x] = q;
    __syncthreads();
    if (threadIdx.x < 128) {
        atomAddF(&sums[f],  ls[threadIdx.x] + ls[threadIdx.x + 128]);
        atomAddF(&sumsq[f], lq[threadIdx.x] + lq[threadIdx.x + 128]);
    }
}

__global__ void k_bn_final(const float* __restrict__ bn, const float* __restrict__ gamma,
                           const float* __restrict__ beta, float* __restrict__ scale,
                           float* __restrict__ shift, int n)
{
    int f = threadIdx.x;
    if (f < 128) {
        float inv_n = 1.0f / (float)n;
        float mu  = bn[f] * inv_n;
        float var = bn[128 + f] * inv_n - mu * mu;
        float rstd = rsqrtf(var + 1e-5f);
        float sc = gamma[f] * rstd;
        scale[f] = sc;
        shift[f] = beta[f] - mu * sc;
    }
}

extern "C" void kernel_launch(void* const* d_in, const int* in_sizes, int n_in,
                              void* d_out, int out_size, void* d_ws, size_t ws_size,
                              hipStream_t stream)
{
    const float* x     = (const float*)d_in[0];
    const int*   ei    = (const int*)  d_in[1];
    const float* ew    = (const float*)d_in[2];
    const float* W1    = (const float*)d_in[3];
    const float* b1    = (const float*)d_in[4];
    const float* gamma = (const float*)d_in[5];
    const float* beta  = (const float*)d_in[6];
    const float* W2    = (const float*)d_in[7];
    const float* b2    = (const float*)d_in[8];

    const int n = in_sizes[0] / 128;   // 100000
    const int e = in_sizes[2];         // 1600000
    const int* row = ei;               // edge_index[0]  (source)
    const int* col = ei + e;           // edge_index[1]  (target)

    // workspace layout (4-byte units):
    // dinv[n] | h1 bf16[n*128] (h2 aliases) | agg1 f32[n*128] (rank aliases) |
    // bn[256] | scale[128] | shift[128] | cnt[n] | ptr[n+1] | bsum[1024] |
    // w1f[8192 f32] | w2f[4096 f32] | csr[e] (int2)
    float* ws    = (float*)d_ws;
    size_t off   = 0;
    float* dinv  = ws + off; off += n;
    ushort* h1   = (ushort*)(ws + off); off += (size_t)n * 64;  // n*128 bf16
    float* agg1  = ws + off; off += (size_t)n * 128;
    float* bn    = ws + off; off += 256;
    float* scale = ws + off; off += 128;
    float* shift = ws + off; off += 128;
    int*   cnt   = (int*)(ws + off); off += n;
    int*   ptr   = (int*)(ws + off); off += (size_t)(n + 1);
    int*   bsum  = (int*)(ws + off); off += 1024;
    off = (off + 3) & ~(size_t)3;       // 16-byte align for uint4
    uint4* w1f   = (uint4*)(ws + off); off += 8192;  // 128*128 bf16 = 2048 uint4
    uint4* w2f   = (uint4*)(ws + off); off += 4096;  // 128*64  bf16 = 1024 uint4
    int2*  csr   = (int2*)(ws + off);
    int*   rank  = (int*)agg1;          // agg1 dead until k_gather1
    ushort* h2   = h1;                  // h1 dead after k_gather1
    float* outp  = (float*)d_out;

    const int nb_n = (n + 255) / 256;
    const int nb_e = (e + 255) / 256;
    const int nb_wpn = (n + 3) / 4;     // wave-per-node: n*64 threads
    const int nb_qpn = (n + 15) / 16;   // 16-lane-group-per-node
    const int nb_mf  = (n + 63) / 64;   // MFMA gemm: 64 rows/block
    const int nblk_scan = (n + 1023) / 1024;   // 98 <= 1024

    // W fragment swizzle (no deps)
    k_wfrag<<<8, 256, 0, stream>>>(W1, w1f, 128);
    k_wfrag<<<4, 256, 0, stream>>>(W2, w2f, 64);

    // CSR build: count(+rank) -> scan -> fill -> degsum
    k_init<<<nb_n, 256, 0, stream>>>(cnt, bn, n);
    k_cnt<<<nb_e, 256, 0, stream>>>(col, cnt, rank, e);
    k_scanA<<<nblk_scan, 256, 0, stream>>>(cnt, bsum, n);
    k_scanB<<<1, 1024, 0, stream>>>(bsum, ptr, nblk_scan, n);
    k_scanC<<<nblk_scan, 256, 0, stream>>>(cnt, bsum, ptr, n);
    k_fill<<<nb_e, 256, 0, stream>>>(row, col, ew, rank, ptr, csr, e);
    k_degsum<<<nb_qpn, 256, 0, stream>>>(ptr, csr, dinv, n);

    // ---- layer 1: h1 = x @ W1 (bf16, MFMA) ; agg1 = gather(h1) + b1 ----
    k_mfma<128, false><<<nb_mf, 256, 0, stream>>>(x, w1f, nullptr, nullptr, h1, n);
    k_gather1<<<nb_qpn, 256, 0, stream>>>(ptr, csr, h1, dinv, b1, agg1, n);

    // ---- batchnorm stats -> scale/shift ----
    k_bn_stats<<<256, 256, 0, stream>>>(agg1, bn, bn + 128, n);
    k_bn_final<<<1, 128, 0, stream>>>(bn, gamma, beta, scale, shift, n);

    // ---- layer 2: h2 = relu(bn(agg1)) @ W2 (bf16, MFMA) ; out + lsm ----
    k_mfma<64, true><<<nb_mf, 256, 0, stream>>>(agg1, w2f, scale, shift, h2, n);
    k_gather2<<<nb_wpn, 256, 0, stream>>>(ptr, csr, h2, dinv, b2, outp, n);
}

// Round 10
// 290.011 us; speedup vs baseline: 1.5245x; 1.2103x over previous
//
#include <hip/hip_runtime.h>
#include <math.h>

// ---------------------------------------------------------------------------
// TrafficGNN: 2-layer GCN + BN + ReLU + log_softmax.
// Round 10: (a) k_gather2 remapped to 8-lane-group-per-node (8 nodes/wave,
// uint4 h-loads, group-local log_softmax) — same fix that won on gather1;
// (b) agg1 stored bf16 (halves gather1 write, bn_stats read, mfma64 A-read).
// ---------------------------------------------------------------------------

typedef unsigned int   uint;
typedef unsigned short ushort;
typedef __bf16 bf16x8 __attribute__((ext_vector_type(8)));
typedef float  f32x4  __attribute__((ext_vector_type(4)));

union U16 { uint4 u; bf16x8 b; };

__device__ __forceinline__ void atomAddF(float* p, float v) {
    __hip_atomic_fetch_add(p, v, __ATOMIC_RELAXED, __HIP_MEMORY_SCOPE_AGENT);
}

// float -> bf16 (round to nearest even)
__device__ __forceinline__ ushort f2bf(float f) {
    uint u = __float_as_uint(f);
    u += 0x7FFFu + ((u >> 16) & 1u);
    return (ushort)(u >> 16);
}
__device__ __forceinline__ float bf2f(ushort h) {
    return __uint_as_float(((uint)h) << 16);
}
__device__ __forceinline__ uint pack2(float f0, float f1) {
    return (uint)f2bf(f0) | ((uint)f2bf(f1) << 16);
}

// zero edge counters + zero BN accumulators
__global__ void k_init(int* __restrict__ cnt, float* __restrict__ bn, int n) {
    int i = blockIdx.x * 256 + threadIdx.x;
    if (i < n) cnt[i] = 0;
    if (i < 256) bn[i] = 0.0f;   // bn[0..127]=sum, bn[128..255]=sumsq
}

// rank[i] = slot index of edge i within its target's segment
__global__ void k_cnt(const int* __restrict__ col, int* __restrict__ cnt,
                      int* __restrict__ rank, int e) {
    int i = blockIdx.x * 256 + threadIdx.x;
    if (i < e) rank[i] = atomicAdd(&cnt[col[i]], 1);
}

// ---- exclusive scan of cnt[n] -> ptr[n+1] ----

__global__ __launch_bounds__(256)
void k_scanA(const int* __restrict__ cnt, int* __restrict__ bsum, int n) {
    __shared__ int ls[256];
    int base = blockIdx.x * 1024 + threadIdx.x * 4;
    int s = 0;
#pragma unroll
    for (int k = 0; k < 4; ++k) { int i = base + k; if (i < n) s += cnt[i]; }
    ls[threadIdx.x] = s;
    __syncthreads();
    for (int d = 128; d > 0; d >>= 1) {
        if (threadIdx.x < d) ls[threadIdx.x] += ls[threadIdx.x + d];
        __syncthreads();
    }
    if (threadIdx.x == 0) bsum[blockIdx.x] = ls[0];
}

// parallel exclusive scan of block sums (nblk <= 1024); also ptr[n] = total
__global__ __launch_bounds__(1024)
void k_scanB(int* __restrict__ bsum, int* __restrict__ ptr, int nblk, int n) {
    __shared__ int ls[1024];
    int t = threadIdx.x;
    int v = (t < nblk) ? bsum[t] : 0;
    ls[t] = v;
    __syncthreads();
    for (int d = 1; d < 1024; d <<= 1) {
        int mine = ls[t];
        int up   = (t >= d) ? ls[t - d] : 0;
        __syncthreads();
        ls[t] = mine + up;
        __syncthreads();
    }
    if (t < nblk) bsum[t] = ls[t] - v;   // exclusive
    if (t == 0) ptr[n] = ls[1023];       // total
}

__global__ __launch_bounds__(256)
void k_scanC(const int* __restrict__ cnt, const int* __restrict__ bsum,
             int* __restrict__ ptr, int n) {
    __shared__ int ls[256];
    int base = blockIdx.x * 1024 + threadIdx.x * 4;
    int v[4];
#pragma unroll
    for (int k = 0; k < 4; ++k) { int i = base + k; v[k] = (i < n) ? cnt[i] : 0; }
    int t = v[0] + v[1] + v[2] + v[3];
    ls[threadIdx.x] = t;
    __syncthreads();
    for (int d = 1; d < 256; d <<= 1) {
        int mine = ls[threadIdx.x];
        int up   = (threadIdx.x >= d) ? ls[threadIdx.x - d] : 0;
        __syncthreads();
        ls[threadIdx.x] = mine + up;
        __syncthreads();
    }
    int off = bsum[blockIdx.x] + ls[threadIdx.x] - t;   // exclusive
    int pf = 0;
#pragma unroll
    for (int k = 0; k < 4; ++k) {
        int i = base + k;
        if (i < n) ptr[i] = off + pf;
        pf += v[k];
    }
}

// atomic-free CSR fill: slot = ptr[tgt] + rank; store (src, raw ew) pair
__global__ void k_fill(const int* __restrict__ row, const int* __restrict__ col,
                       const float* __restrict__ ew, const int* __restrict__ rank,
                       const int* __restrict__ ptr, int2* __restrict__ csr, int e) {
    int i = blockIdx.x * 256 + threadIdx.x;
    if (i < e) {
        int pos = ptr[col[i]] + rank[i];
        int2 pr;
        pr.x = row[i];
        pr.y = __float_as_int(ew[i]);
        csr[pos] = pr;
    }
}

// dinv[i] = rsqrt(1 + sum of raw ew over segment)    (16 lanes per node)
__global__ __launch_bounds__(256)
void k_degsum(const int* __restrict__ ptr, const int2* __restrict__ csr,
              float* __restrict__ dinv, int n) {
    int lane = threadIdx.x & 15;
    int node = (blockIdx.x * 256 + threadIdx.x) >> 4;
    if (node >= n) return;
    int p0 = ptr[node], p1 = ptr[node + 1];
    float s = 0.f;
    for (int j = p0 + lane; j < p1; j += 16) s += __int_as_float(csr[j].y);
#pragma unroll
    for (int off = 8; off > 0; off >>= 1) s += __shfl_xor(s, off, 16);
    if (lane == 0) dinv[node] = rsqrtf(1.0f + s);
}

// W[128][M] f32 row-major -> bf16 fragment order (one thread per fragment)
__global__ void k_wfrag(const float* __restrict__ W, uint4* __restrict__ Wf, int M) {
    int t = blockIdx.x * 256 + threadIdx.x;
    if (t >= M * 16) return;
    int l  = t & 63;
    int ks = (t >> 6) & 3;
    int nt = t >> 8;
    int kbase = ks * 32 + (l >> 4) * 8;
    int colj  = nt * 16 + (l & 15);
    float v[8];
#pragma unroll
    for (int j = 0; j < 8; ++j) v[j] = W[(kbase + j) * M + colj];
    uint4 o;
    o.x = pack2(v[0], v[1]);
    o.y = pack2(v[2], v[3]);
    o.z = pack2(v[4], v[5]);
    o.w = pack2(v[6], v[7]);
    Wf[t] = o;
}

// H[n,M](bf16) = X'[n,128] @ W[128,M] via 16x16x32 bf16 MFMA.
// BN=false: X is f32.  BN=true: X is bf16, X' = relu(X*scale+shift).
template<int M, bool BN>
__global__ __launch_bounds__(256)
void k_mfma(const void* __restrict__ Xv, const uint4* __restrict__ Wf,
            const float* __restrict__ scale, const float* __restrict__ shift,
            ushort* __restrict__ H, int n)
{
    constexpr int NT = M / 16;
    const int l = threadIdx.x & 63;
    const int w = threadIdx.x >> 6;
    const int rowbase = blockIdx.x * 64 + w * 16;
    const int arow = rowbase + (l & 15);
    const bool rv = arow < n;
    const int koff = (l >> 4) * 8;

    f32x4 acc[NT];
#pragma unroll
    for (int t = 0; t < NT; ++t) acc[t] = (f32x4){0.f, 0.f, 0.f, 0.f};

#pragma unroll
    for (int ks = 0; ks < 4; ++ks) {
        U16 ua;
        if (BN) {
            const ushort* xr = (const ushort*)Xv + (size_t)arow * 128 + koff;
            U16 xa; xa.u = make_uint4(0, 0, 0, 0);
            if (rv) xa.u = *(const uint4*)(xr + ks * 32);
            int k0 = ks * 32 + koff;
            float4 sc0 = *(const float4*)(scale + k0);
            float4 sc1 = *(const float4*)(scale + k0 + 4);
            float4 sh0 = *(const float4*)(shift + k0);
            float4 sh1 = *(const float4*)(shift + k0 + 4);
            float a[8];
            a[0] = fmaxf(0.f, fmaf(bf2f((ushort)(xa.u.x)),       sc0.x, sh0.x));
            a[1] = fmaxf(0.f, fmaf(bf2f((ushort)(xa.u.x >> 16)), sc0.y, sh0.y));
            a[2] = fmaxf(0.f, fmaf(bf2f((ushort)(xa.u.y)),       sc0.z, sh0.z));
            a[3] = fmaxf(0.f, fmaf(bf2f((ushort)(xa.u.y >> 16)), sc0.w, sh0.w));
            a[4] = fmaxf(0.f, fmaf(bf2f((ushort)(xa.u.z)),       sc1.x, sh1.x));
            a[5] = fmaxf(0.f, fmaf(bf2f((ushort)(xa.u.z >> 16)), sc1.y, sh1.y));
            a[6] = fmaxf(0.f, fmaf(bf2f((ushort)(xa.u.w)),       sc1.z, sh1.z));
            a[7] = fmaxf(0.f, fmaf(bf2f((ushort)(xa.u.w >> 16)), sc1.w, sh1.w));
            ua.u.x = pack2(a[0], a[1]);
            ua.u.y = pack2(a[2], a[3]);
            ua.u.z = pack2(a[4], a[5]);
            ua.u.w = pack2(a[6], a[7]);
        } else {
            const float* xr = (const float*)Xv + (size_t)arow * 128 + koff;
            float4 a0 = make_float4(0.f, 0.f, 0.f, 0.f);
            float4 a1 = a0;
            if (rv) {
                a0 = *(const float4*)(xr + ks * 32);
                a1 = *(const float4*)(xr + ks * 32 + 4);
            }
            ua.u.x = pack2(a0.x, a0.y);
            ua.u.y = pack2(a0.z, a0.w);
            ua.u.z = pack2(a1.x, a1.y);
            ua.u.w = pack2(a1.z, a1.w);
        }
#pragma unroll
        for (int nt = 0; nt < NT; ++nt) {
            U16 ub;
            ub.u = Wf[(nt * 4 + ks) * 64 + l];
            acc[nt] = __builtin_amdgcn_mfma_f32_16x16x32_bf16(ua.b, ub.b, acc[nt], 0, 0, 0);
        }
    }

    // epilogue: transpose through padded LDS, then coalesced 16B stores.
    __shared__ __align__(16) ushort lds[4][16][M + 8];
#pragma unroll
    for (int nt = 0; nt < NT; ++nt)
#pragma unroll
        for (int r = 0; r < 4; ++r)
            lds[w][(l >> 4) * 4 + r][nt * 16 + (l & 15)] = f2bf(acc[nt][r]);
    __syncthreads();

    constexpr int LPR = M / 8;
    constexpr int RPP = 64 / LPR;
#pragma unroll
    for (int it = 0; it < 16 / RPP; ++it) {
        int rl = it * RPP + (l / LPR);
        int gr = rowbase + rl;
        if (gr < n)
            *(uint4*)(H + (size_t)gr * M + (l % LPR) * 8) =
                *(const uint4*)&lds[w][rl][(l % LPR) * 8];
    }
}

// layer-1 gather, 16-lane group per node (4 nodes/wave):
// out bf16 = b1 + h[i]*dinv^2 + sum h[src]*(ew*dinv[src]*di); h bf16[n][128]
__global__ __launch_bounds__(256)
void k_gather1(const int* __restrict__ ptr, const int2* __restrict__ csr,
               const ushort* __restrict__ h, const float* __restrict__ dinv,
               const float* __restrict__ bias, ushort* __restrict__ out, int n)
{
    int lane = threadIdx.x & 15;
    int node = (blockIdx.x * 256 + threadIdx.x) >> 4;
    if (node >= n) return;
    int p0 = ptr[node], p1 = ptr[node + 1];
    float di = dinv[node];
    float s  = di * di;

    U16 hv; hv.u = *(const uint4*)(h + (size_t)node * 128 + lane * 8);
    float4 b0 = *(const float4*)(bias + lane * 8);
    float4 b1v = *(const float4*)(bias + lane * 8 + 4);
    float acc[8];
    acc[0] = fmaf(bf2f((ushort)(hv.u.x)),       s, b0.x);
    acc[1] = fmaf(bf2f((ushort)(hv.u.x >> 16)), s, b0.y);
    acc[2] = fmaf(bf2f((ushort)(hv.u.y)),       s, b0.z);
    acc[3] = fmaf(bf2f((ushort)(hv.u.y >> 16)), s, b0.w);
    acc[4] = fmaf(bf2f((ushort)(hv.u.z)),       s, b1v.x);
    acc[5] = fmaf(bf2f((ushort)(hv.u.z >> 16)), s, b1v.y);
    acc[6] = fmaf(bf2f((ushort)(hv.u.w)),       s, b1v.z);
    acc[7] = fmaf(bf2f((ushort)(hv.u.w >> 16)), s, b1v.w);

#pragma unroll 4
    for (int j = p0; j < p1; ++j) {
        int2 pr = csr[j];
        float w = __int_as_float(pr.y) * di * dinv[pr.x];
        U16 v; v.u = *(const uint4*)(h + (size_t)pr.x * 128 + lane * 8);
        acc[0] = fmaf(bf2f((ushort)(v.u.x)),       w, acc[0]);
        acc[1] = fmaf(bf2f((ushort)(v.u.x >> 16)), w, acc[1]);
        acc[2] = fmaf(bf2f((ushort)(v.u.y)),       w, acc[2]);
        acc[3] = fmaf(bf2f((ushort)(v.u.y >> 16)), w, acc[3]);
        acc[4] = fmaf(bf2f((ushort)(v.u.z)),       w, acc[4]);
        acc[5] = fmaf(bf2f((ushort)(v.u.z >> 16)), w, acc[5]);
        acc[6] = fmaf(bf2f((ushort)(v.u.w)),       w, acc[6]);
        acc[7] = fmaf(bf2f((ushort)(v.u.w >> 16)), w, acc[7]);
    }

    U16 o;
    o.u.x = pack2(acc[0], acc[1]);
    o.u.y = pack2(acc[2], acc[3]);
    o.u.z = pack2(acc[4], acc[5]);
    o.u.w = pack2(acc[6], acc[7]);
    *(uint4*)(out + (size_t)node * 128 + lane * 8) = o.u;
}

// layer-2 gather + fused log_softmax, 8-lane group per node (8 nodes/wave):
// each lane owns 8 of the 64 features (one uint4 load per edge).
__global__ __launch_bounds__(256)
void k_gather2(const int* __restrict__ ptr, const int2* __restrict__ csr,
               const ushort* __restrict__ h, const float* __restrict__ dinv,
               const float* __restrict__ bias, float* __restrict__ out, int n)
{
    int lane = threadIdx.x & 7;
    int node = (blockIdx.x * 256 + threadIdx.x) >> 3;
    if (node >= n) return;
    int p0 = ptr[node], p1 = ptr[node + 1];
    float di = dinv[node];
    float s  = di * di;

    U16 hv; hv.u = *(const uint4*)(h + (size_t)node * 64 + lane * 8);
    float4 b0 = *(const float4*)(bias + lane * 8);
    float4 b1v = *(const float4*)(bias + lane * 8 + 4);
    float acc[8];
    acc[0] = fmaf(bf2f((ushort)(hv.u.x)),       s, b0.x);
    acc[1] = fmaf(bf2f((ushort)(hv.u.x >> 16)), s, b0.y);
    acc[2] = fmaf(bf2f((ushort)(hv.u.y)),       s, b0.z);
    acc[3] = fmaf(bf2f((ushort)(hv.u.y >> 16)), s, b0.w);
    acc[4] = fmaf(bf2f((ushort)(hv.u.z)),       s, b1v.x);
    acc[5] = fmaf(bf2f((ushort)(hv.u.z >> 16)), s, b1v.y);
    acc[6] = fmaf(bf2f((ushort)(hv.u.w)),       s, b1v.z);
    acc[7] = fmaf(bf2f((ushort)(hv.u.w >> 16)), s, b1v.w);

#pragma unroll 4
    for (int j = p0; j < p1; ++j) {
        int2 pr = csr[j];
        float w = __int_as_float(pr.y) * di * dinv[pr.x];
        U16 v; v.u = *(const uint4*)(h + (size_t)pr.x * 64 + lane * 8);
        acc[0] = fmaf(bf2f((ushort)(v.u.x)),       w, acc[0]);
        acc[1] = fmaf(bf2f((ushort)(v.u.x >> 16)), w, acc[1]);
        acc[2] = fmaf(bf2f((ushort)(v.u.y)),       w, acc[2]);
        acc[3] = fmaf(bf2f((ushort)(v.u.y >> 16)), w, acc[3]);
        acc[4] = fmaf(bf2f((ushort)(v.u.z)),       w, acc[4]);
        acc[5] = fmaf(bf2f((ushort)(v.u.z >> 16)), w, acc[5]);
        acc[6] = fmaf(bf2f((ushort)(v.u.w)),       w, acc[6]);
        acc[7] = fmaf(bf2f((ushort)(v.u.w >> 16)), w, acc[7]);
    }

    // log_softmax over the group's 64 features (8 in-lane + 8 lanes)
    float m = acc[0];
#pragma unroll
    for (int k = 1; k < 8; ++k) m = fmaxf(m, acc[k]);
#pragma unroll
    for (int off = 1; off < 8; off <<= 1) m = fmaxf(m, __shfl_xor(m, off, 64));
    float sum = 0.f;
#pragma unroll
    for (int k = 0; k < 8; ++k) sum += expf(acc[k] - m);
#pragma unroll
    for (int off = 1; off < 8; off <<= 1) sum += __shfl_xor(sum, off, 64);
    float lse = m + logf(sum);

    float* orow = out + (size_t)node * 64 + lane * 8;
    *(float4*)(orow)     = make_float4(acc[0] - lse, acc[1] - lse, acc[2] - lse, acc[3] - lse);
    *(float4*)(orow + 4) = make_float4(acc[4] - lse, acc[5] - lse, acc[6] - lse, acc[7] - lse);
}

// per-feature sum & sumsq over nodes; a is bf16[n][128]
__global__ __launch_bounds__(256)
void k_bn_stats(const ushort* __restrict__ a, float* __restrict__ sums,
                float* __restrict__ sumsq, int n)
{
    int fp = threadIdx.x & 63;       // feature pair
    int rg = threadIdx.x >> 6;       // row group 0..3
    float s0 = 0.f, q0 = 0.f, s1 = 0.f, q1 = 0.f;
    for (int r = blockIdx.x * 4 + rg; r < n; r += gridDim.x * 4) {
        uint v = *(const uint*)(a + (size_t)r * 128 + fp * 2);
        float x0 = bf2f((ushort)v), x1 = bf2f((ushort)(v >> 16));
        s0 += x0; q0 += x0 * x0;
        s1 += x1; q1 += x1 * x1;
    }
    __shared__ float l0[256], l1[256], l2[256], l3[256];
    l0[threadIdx.x] = s0; l1[threadIdx.x] = q0;
    l2[threadIdx.x] = s1; l3[threadIdx.x] = q1;
    __syncthreads();
    if (rg == 0) {
        float S0 = l0[fp] + l0[fp + 64] + l0[fp + 128] + l0[fp + 192];
        float Q0 = l1[fp] + l1[fp + 64] + l1[fp + 128] + l1[fp + 192];
        float S1 = l2[fp] + l2[fp + 64] + l2[fp + 128] + l2[fp + 192];
        float Q1 = l3[fp] + l3[fp + 64] + l3[fp + 128] + l3[fp + 192];
        atomAddF(&sums[fp * 2],     S0);
        atomAddF(&sumsq[fp * 2],    Q0);
        atomAddF(&sums[fp * 2 + 1], S1);
        atomAddF(&sumsq[fp * 2 + 1], Q1);
    }
}

__global__ void k_bn_final(const float* __restrict__ bn, const float* __restrict__ gamma,
                           const float* __restrict__ beta, float* __restrict__ scale,
                           float* __restrict__ shift, int n)
{
    int f = threadIdx.x;
    if (f < 128) {
        float inv_n = 1.0f / (float)n;
        float mu  = bn[f] * inv_n;
        float var = bn[128 + f] * inv_n - mu * mu;
        float rstd = rsqrtf(var + 1e-5f);
        float sc = gamma[f] * rstd;
        scale[f] = sc;
        shift[f] = beta[f] - mu * sc;
    }
}

extern "C" void kernel_launch(void* const* d_in, const int* in_sizes, int n_in,
                              void* d_out, int out_size, void* d_ws, size_t ws_size,
                              hipStream_t stream)
{
    const float* x     = (const float*)d_in[0];
    const int*   ei    = (const int*)  d_in[1];
    const float* ew    = (const float*)d_in[2];
    const float* W1    = (const float*)d_in[3];
    const float* b1    = (const float*)d_in[4];
    const float* gamma = (const float*)d_in[5];
    const float* beta  = (const float*)d_in[6];
    const float* W2    = (const float*)d_in[7];
    const float* b2    = (const float*)d_in[8];

    const int n = in_sizes[0] / 128;   // 100000
    const int e = in_sizes[2];         // 1600000
    const int* row = ei;               // edge_index[0]  (source)
    const int* col = ei + e;           // edge_index[1]  (target)

    // workspace layout (4-byte units):
    // dinv[n] | h1 bf16[n*128] (h2 aliases) | agg1 bf16[n*128] (rank aliases) |
    // bn[256] | scale[128] | shift[128] | cnt[n] | ptr[n+1] | bsum[1024] |
    // w1f[8192 f32] | w2f[4096 f32] | csr[e] (int2)
    float* ws    = (float*)d_ws;
    size_t off   = 0;
    float* dinv  = ws + off; off += n;
    ushort* h1   = (ushort*)(ws + off); off += (size_t)n * 64;  // n*128 bf16
    ushort* agg1 = (ushort*)(ws + off); off += (size_t)n * 64;  // n*128 bf16
    float* bn    = ws + off; off += 256;
    float* scale = ws + off; off += 128;
    float* shift = ws + off; off += 128;
    int*   cnt   = (int*)(ws + off); off += n;
    int*   ptr   = (int*)(ws + off); off += (size_t)(n + 1);
    int*   bsum  = (int*)(ws + off); off += 1024;
    off = (off + 3) & ~(size_t)3;       // 16-byte align for uint4
    uint4* w1f   = (uint4*)(ws + off); off += 8192;  // 128*128 bf16 = 2048 uint4
    uint4* w2f   = (uint4*)(ws + off); off += 4096;  // 128*64  bf16 = 1024 uint4
    int2*  csr   = (int2*)(ws + off);
    int*   rank  = (int*)agg1;          // agg1 dead until k_gather1
    ushort* h2   = h1;                  // h1 dead after k_gather1
    float* outp  = (float*)d_out;

    const int nb_n = (n + 255) / 256;
    const int nb_e = (e + 255) / 256;
    const int nb_qpn = (n + 15) / 16;   // 16-lane-group-per-node
    const int nb_opn = (n + 31) / 32;   // 8-lane-group-per-node
    const int nb_mf  = (n + 63) / 64;   // MFMA gemm: 64 rows/block
    const int nblk_scan = (n + 1023) / 1024;   // 98 <= 1024

    // W fragment swizzle (no deps)
    k_wfrag<<<8, 256, 0, stream>>>(W1, w1f, 128);
    k_wfrag<<<4, 256, 0, stream>>>(W2, w2f, 64);

    // CSR build: count(+rank) -> scan -> fill -> degsum
    k_init<<<nb_n, 256, 0, stream>>>(cnt, bn, n);
    k_cnt<<<nb_e, 256, 0, stream>>>(col, cnt, rank, e);
    k_scanA<<<nblk_scan, 256, 0, stream>>>(cnt, bsum, n);
    k_scanB<<<1, 1024, 0, stream>>>(bsum, ptr, nblk_scan, n);
    k_scanC<<<nblk_scan, 256, 0, stream>>>(cnt, bsum, ptr, n);
    k_fill<<<nb_e, 256, 0, stream>>>(row, col, ew, rank, ptr, csr, e);
    k_degsum<<<nb_qpn, 256, 0, stream>>>(ptr, csr, dinv, n);

    // ---- layer 1: h1 = x @ W1 (bf16, MFMA) ; agg1 = gather(h1) + b1 (bf16) ----
    k_mfma<128, false><<<nb_mf, 256, 0, stream>>>(x, w1f, nullptr, nullptr, h1, n);
    k_gather1<<<nb_qpn, 256, 0, stream>>>(ptr, csr, h1, dinv, b1, agg1, n);

    // ---- batchnorm stats -> scale/shift ----
    k_bn_stats<<<256, 256, 0, stream>>>(agg1, bn, bn + 128, n);
    k_bn_final<<<1, 128, 0, stream>>>(bn, gamma, beta, scale, shift, n);

    // ---- layer 2: h2 = relu(bn(agg1)) @ W2 (bf16, MFMA) ; out + lsm ----
    k_mfma<64, true><<<nb_mf, 256, 0, stream>>>(agg1, w2f, scale, shift, h2, n);
    k_gather2<<<nb_opn, 256, 0, stream>>>(ptr, csr, h2, dinv, b2, outp, n);
}